// Round 1
// 24081.831 us; speedup vs baseline: 1.1245x; 1.1245x over previous
//
#include <hip/hip_runtime.h>
#include <math.h>

// Problem constants: IN=1662, H=512, T=256, B=128, C=100
// Outputs: logits [128,100] then attw [128,256,1]

typedef __attribute__((ext_vector_type(8))) short bf16x8;
typedef __attribute__((ext_vector_type(4))) float f32x4;

__device__ __forceinline__ ushort f2bf(float f) {
    uint u = __float_as_uint(f);
    uint r = (u + 0x7FFFu + ((u >> 16) & 1u)) >> 16;
    return (ushort)r;
}
__device__ __forceinline__ float bf2f(ushort h) {
    return __uint_as_float(((uint)h) << 16);
}
__device__ __forceinline__ float sigm(float x) { return 1.f / (1.f + __expf(-x)); }
__device__ __forceinline__ float tanhfast(float x) {
    float xx = fminf(fmaxf(x, -9.f), 9.f);
    float e = __expf(2.f * xx);
    return (e - 1.f) / (e + 1.f);
}

// ---------------------------------------------------------------------------
// Split-bf16 MFMA GEMM: C[M,N] = A[M,K] @ W^T + bias   (unchanged)
// ---------------------------------------------------------------------------
__global__ void __launch_bounds__(256, 2)
gemm_mfma_bt(const float* __restrict__ A, int lda,
             const float* __restrict__ W, int ldw,
             const float* __restrict__ bias,
             float* __restrict__ C, long ldc, int K)
{
    __shared__ ushort Ahi[128][40];
    __shared__ ushort Alo[128][40];
    __shared__ ushort Bhi[128][40];
    __shared__ ushort Blo[128][40];

    const int tid  = threadIdx.x;
    const int bm   = blockIdx.y * 128;
    const int bn   = blockIdx.x * 128;
    const int wave = tid >> 6, lane = tid & 63;
    const int wr = wave >> 1, wc = wave & 1;
    const int quad = lane >> 4, l16 = lane & 15;

    f32x4 acc[4][4];
#pragma unroll
    for (int i = 0; i < 4; ++i)
#pragma unroll
        for (int j = 0; j < 4; ++j)
            acc[i][j] = (f32x4){0.f, 0.f, 0.f, 0.f};

    for (int k0 = 0; k0 < K; k0 += 32) {
        const int kw = (K - k0 < 32) ? (K - k0) : 32;
#pragma unroll
        for (int i = 0; i < 8; ++i) {
            int f = i * 256 + tid;
            int row = f >> 4, kp = f & 15;
            float2 v = make_float2(0.f, 0.f);
            if (2 * kp < kw)
                v = *(const float2*)(A + (size_t)(bm + row) * lda + k0 + 2 * kp);
            ushort hx = f2bf(v.x), hy = f2bf(v.y);
            ushort lx = f2bf(v.x - bf2f(hx)), ly = f2bf(v.y - bf2f(hy));
            *(uint*)&Ahi[row][2 * kp] = (uint)hx | ((uint)hy << 16);
            *(uint*)&Alo[row][2 * kp] = (uint)lx | ((uint)ly << 16);
        }
#pragma unroll
        for (int i = 0; i < 8; ++i) {
            int f = i * 256 + tid;
            int row = f >> 4, kp = f & 15;
            float2 v = make_float2(0.f, 0.f);
            if (2 * kp < kw)
                v = *(const float2*)(W + (size_t)(bn + row) * ldw + k0 + 2 * kp);
            ushort hx = f2bf(v.x), hy = f2bf(v.y);
            ushort lx = f2bf(v.x - bf2f(hx)), ly = f2bf(v.y - bf2f(hy));
            *(uint*)&Bhi[row][2 * kp] = (uint)hx | ((uint)hy << 16);
            *(uint*)&Blo[row][2 * kp] = (uint)lx | ((uint)ly << 16);
        }
        __syncthreads();

        bf16x8 ah[4], al[4], bh[4], bl[4];
#pragma unroll
        for (int i = 0; i < 4; ++i) {
            int m = wr * 64 + i * 16 + l16;
            ah[i] = *(const bf16x8*)&Ahi[m][quad * 8];
            al[i] = *(const bf16x8*)&Alo[m][quad * 8];
            int n = wc * 64 + i * 16 + l16;
            bh[i] = *(const bf16x8*)&Bhi[n][quad * 8];
            bl[i] = *(const bf16x8*)&Blo[n][quad * 8];
        }
#pragma unroll
        for (int i = 0; i < 4; ++i)
#pragma unroll
            for (int j = 0; j < 4; ++j) {
                acc[i][j] = __builtin_amdgcn_mfma_f32_16x16x32_bf16(ah[i], bh[j], acc[i][j], 0, 0, 0);
                acc[i][j] = __builtin_amdgcn_mfma_f32_16x16x32_bf16(ah[i], bl[j], acc[i][j], 0, 0, 0);
                acc[i][j] = __builtin_amdgcn_mfma_f32_16x16x32_bf16(al[i], bh[j], acc[i][j], 0, 0, 0);
            }
        __syncthreads();
    }

#pragma unroll
    for (int j = 0; j < 4; ++j) {
        int n = bn + wc * 64 + j * 16 + l16;
        float bv = bias ? bias[n] : 0.f;
#pragma unroll
        for (int i = 0; i < 4; ++i) {
            int mb = bm + wr * 64 + i * 16 + quad * 4;
#pragma unroll
            for (int r = 0; r < 4; ++r)
                C[(size_t)(mb + r) * ldc + n] = acc[i][j][r] + bv;
        }
    }
}

// 1024x1024 transpose: out[n][k] = in[k][n]
__global__ void __launch_bounds__(256)
transpose1024(const float* __restrict__ in, float* __restrict__ out)
{
    __shared__ float tile[32][33];
    int bx = blockIdx.x * 32, by = blockIdx.y * 32;
    int tx = threadIdx.x & 31, ty = threadIdx.x >> 5;
    for (int i = 0; i < 32; i += 8)
        tile[ty + i][tx] = in[(size_t)(by + ty + i) * 1024 + bx + tx];
    __syncthreads();
    for (int i = 0; i < 32; i += 8)
        out[(size_t)(bx + ty + i) * 1024 + by + tx] = tile[tx][ty + i];
}

// ---------------------------------------------------------------------------
// Pack w_hh [2048,512] fp32 (one direction) -> gate-packed split-bf16 planes
//   NEW layout for 128-block persistent kernel:
//   dest [64 jg][32 p][512 k], p = g*8 + (j&7), jg = j>>3, row = g*512 + j
// ---------------------------------------------------------------------------
__global__ void __launch_bounds__(256)
pack_whh32(const float* __restrict__ w, ushort* __restrict__ hi, ushort* __restrict__ lo)
{
    int idx = blockIdx.x * 256 + threadIdx.x;     // 2048*256 = 524288
    int r = idx >> 8;
    int kp = (idx & 255) * 2;
    float2 v = *(const float2*)&w[(size_t)r * 512 + kp];
    int g = r >> 9, j = r & 511, jg = j >> 3, jj = j & 7;
    int p = g * 8 + jj;
    size_t o = ((size_t)jg * 32 + p) * 512 + kp;
    ushort hx = f2bf(v.x), hy = f2bf(v.y);
    *(uint*)&hi[o] = (uint)hx | ((uint)hy << 16);
    *(uint*)&lo[o] = (uint)f2bf(v.x - bf2f(hx)) | ((uint)f2bf(v.y - bf2f(hy)) << 16);
}

// ---------------------------------------------------------------------------
// Persistent LSTM layer: one launch runs all 256 timesteps for both dirs.
// Grid: 128 blocks x 256 threads (dir = blk>>6, jg = blk&63 -> 8 j's, N=32).
// Weights staged once in LDS (64 KB, XOR-swizzled). c-state in registers.
// Cross-step sync: device-scope spin grid-barrier (all 128 blocks resident:
// 128 <= 256 CUs, 84 KB LDS -> 1 block/CU max constraint satisfied trivially).
// ---------------------------------------------------------------------------
#define PERSIST_NBLK 128
#define PERSIST_LDS  (65536 + 128 * 36 * 4)   // weights 64KB + zbuf [128][36]

__global__ void __launch_bounds__(256)
lstm_persist(const ushort* __restrict__ w_hi, const ushort* __restrict__ w_lo, // [2][64][32][512]
             ushort* __restrict__ hA_hi, ushort* __restrict__ hA_lo,
             ushort* __restrict__ hB_hi, ushort* __restrict__ hB_lo,
             const float* __restrict__ xf, const float* __restrict__ xb,  // xproj per dir [B*T,2048]
             float* __restrict__ out,    // [B,T,1024]
             unsigned* __restrict__ barp)
{
    extern __shared__ __align__(16) char smem[];
    ushort* wlds = (ushort*)smem;            // [hi 16384][lo 16384] ushorts, swizzled
    float*  zbuf = (float*)(smem + 65536);   // [128][36]

    const int tid  = threadIdx.x;
    const int dir  = blockIdx.x >> 6;
    const int jg   = blockIdx.x & 63;
    const int wave = tid >> 6, lane = tid & 63;
    const int quad = lane >> 4, l16 = lane & 15;

    // ---- one-time: stage this block's weight slice into LDS (swizzled) ----
    {
        const ushort* wh = w_hi + ((size_t)dir * 64 + jg) * (32 * 512);
        const ushort* wl = w_lo + ((size_t)dir * 64 + jg) * (32 * 512);
#pragma unroll
        for (int it = 0; it < 8; ++it) {
            int unit = it * 256 + tid;           // 2048 x 16B units per plane
            int p = unit >> 6, k8 = unit & 63;
            int src = p * 512 + k8 * 8;          // ushort index
            int dst = src ^ ((p & 7) << 3);      // XOR-swizzle (16B granules)
            *(uint4*)&wlds[dst]         = *(const uint4*)&wh[src];
            *(uint4*)&wlds[16384 + dst] = *(const uint4*)&wl[src];
        }
    }

    // gate-phase mapping: thread -> batch b, 4 j's starting at jb
    const int b  = tid >> 1;
    const int jb = (tid & 1) * 4;
    const int j0 = jg * 8 + jb;                  // global j (within H=512)
    const float* xbase = dir ? xb : xf;
    float cv[4] = {0.f, 0.f, 0.f, 0.f};          // c-state lives in registers

    const int m0 = wave * 32 + l16;              // A-fragment rows for this wave
    __syncthreads();

    for (int t = 0; t < 256; ++t) {
        const int teff = dir ? (255 - t) : t;

        // xproj prefetch (independent of h -> hides under MFMA)
        const float* xp = xbase + ((size_t)b * 256 + teff) * 2048 + j0;
        f32x4 xi = *(const f32x4*)(xp);
        f32x4 xF = *(const f32x4*)(xp + 512);
        f32x4 xg = *(const f32x4*)(xp + 1024);
        f32x4 xo = *(const f32x4*)(xp + 1536);

        const ushort* hh = ((t & 1) ? hB_hi : hA_hi) + (size_t)dir * 65536;
        const ushort* hl = ((t & 1) ? hB_lo : hA_lo) + (size_t)dir * 65536;

        f32x4 acc[2][2];
#pragma unroll
        for (int mt = 0; mt < 2; ++mt)
#pragma unroll
            for (int nt = 0; nt < 2; ++nt)
                acc[mt][nt] = (f32x4){0.f, 0.f, 0.f, 0.f};

#pragma unroll 4
        for (int c = 0; c < 16; ++c) {
            const int k = c * 32 + quad * 8;
            bf16x8 a0h = *(const bf16x8*)&hh[(size_t)m0 * 512 + k];
            bf16x8 a1h = *(const bf16x8*)&hh[(size_t)(m0 + 16) * 512 + k];
            bf16x8 a0l = *(const bf16x8*)&hl[(size_t)m0 * 512 + k];
            bf16x8 a1l = *(const bf16x8*)&hl[(size_t)(m0 + 16) * 512 + k];
#pragma unroll
            for (int nt = 0; nt < 2; ++nt) {
                int p  = nt * 16 + l16;
                int wi = ((p << 9) + k) ^ ((p & 7) << 3);
                bf16x8 bh = *(const bf16x8*)&wlds[wi];
                bf16x8 bl = *(const bf16x8*)&wlds[16384 + wi];
                acc[0][nt] = __builtin_amdgcn_mfma_f32_16x16x32_bf16(a0h, bh, acc[0][nt], 0, 0, 0);
                acc[0][nt] = __builtin_amdgcn_mfma_f32_16x16x32_bf16(a0h, bl, acc[0][nt], 0, 0, 0);
                acc[0][nt] = __builtin_amdgcn_mfma_f32_16x16x32_bf16(a0l, bh, acc[0][nt], 0, 0, 0);
                acc[1][nt] = __builtin_amdgcn_mfma_f32_16x16x32_bf16(a1h, bh, acc[1][nt], 0, 0, 0);
                acc[1][nt] = __builtin_amdgcn_mfma_f32_16x16x32_bf16(a1h, bl, acc[1][nt], 0, 0, 0);
                acc[1][nt] = __builtin_amdgcn_mfma_f32_16x16x32_bf16(a1l, bh, acc[1][nt], 0, 0, 0);
            }
        }

        // C/D layout: col = lane&15 (= packed p within n-tile), row = quad*4+r
#pragma unroll
        for (int mt = 0; mt < 2; ++mt)
#pragma unroll
            for (int nt = 0; nt < 2; ++nt)
#pragma unroll
                for (int r = 0; r < 4; ++r)
                    zbuf[(wave * 32 + mt * 16 + quad * 4 + r) * 36 + nt * 16 + l16] = acc[mt][nt][r];
        __syncthreads();

        // ---- gate phase (z = zbuf + xproj; c,h update) ----
        f32x4 hvv;
        ushort hhi[4] __attribute__((aligned(8)));
        ushort hlo[4] __attribute__((aligned(8)));
#pragma unroll
        for (int q = 0; q < 4; ++q) {
            int jj = jb + q;
            float vi = zbuf[b * 36 +      jj] + xi[q];
            float vf = zbuf[b * 36 +  8 + jj] + xF[q];
            float vg = zbuf[b * 36 + 16 + jj] + xg[q];
            float vo = zbuf[b * 36 + 24 + jj] + xo[q];
            float c  = sigm(vf) * cv[q] + sigm(vi) * tanhfast(vg);
            cv[q] = c;
            float h = sigm(vo) * tanhfast(c);
            hvv[q] = h;
            ushort hi = f2bf(h);
            hhi[q] = hi;
            hlo[q] = f2bf(h - bf2f(hi));
        }
        {
            size_t hoff = (size_t)dir * 65536 + (size_t)b * 512 + j0;
            ushort* oh = ((t & 1) ? hA_hi : hB_hi) + hoff;
            ushort* ol = ((t & 1) ? hA_lo : hB_lo) + hoff;
            *(uint2*)oh = *(uint2*)hhi;
            *(uint2*)ol = *(uint2*)hlo;
            float* op = out + ((size_t)b * 256 + teff) * 1024 + (size_t)dir * 512 + j0;
            *(f32x4*)op = hvv;
        }

        // ---- grid barrier: release h(t), wait for all blocks ----
        __syncthreads();   // includes vmcnt(0): block's stores complete in L2
        if (tid == 0) {
            __threadfence();  // device-scope release (writeback to coherent point)
            __hip_atomic_fetch_add(barp, 1u, __ATOMIC_RELEASE, __HIP_MEMORY_SCOPE_AGENT);
            unsigned tgt = (unsigned)(PERSIST_NBLK * (t + 1));
            while (__hip_atomic_load(barp, __ATOMIC_ACQUIRE, __HIP_MEMORY_SCOPE_AGENT) < tgt)
                __builtin_amdgcn_s_sleep(1);
            __threadfence();  // device-scope acquire (invalidate stale L1/L2)
        }
        __syncthreads();
    }
}

// ------------------------- attention / classifier tail ---------------------
__global__ void __launch_bounds__(256)
att_score(const float* __restrict__ hidden, const float* __restrict__ aw2,
          const float* __restrict__ ab2, float* __restrict__ scores)
{
    int row = blockIdx.x;
    const float* hrow = hidden + (size_t)row * 1024;
    int tid = threadIdx.x;
    float s = 0.f;
    for (int j = tid; j < 1024; j += 256)
        s += tanhf(hrow[j]) * aw2[j];
    for (int off = 32; off > 0; off >>= 1) s += __shfl_down(s, off);
    __shared__ float red[4];
    if ((tid & 63) == 0) red[tid >> 6] = s;
    __syncthreads();
    if (tid == 0)
        scores[row] = red[0] + red[1] + red[2] + red[3] + ab2[0];
}

__global__ void __launch_bounds__(256)
att_softmax(float* __restrict__ scores, float* __restrict__ attw_out)
{
    int b = blockIdx.x, t = threadIdx.x;
    float v = scores[b * 256 + t];
    __shared__ float red[4];
    float m = v;
    for (int off = 32; off > 0; off >>= 1) m = fmaxf(m, __shfl_down(m, off));
    if ((t & 63) == 0) red[t >> 6] = m;
    __syncthreads();
    float bmax = fmaxf(fmaxf(red[0], red[1]), fmaxf(red[2], red[3]));
    __syncthreads();
    float e = expf(v - bmax);
    float s = e;
    for (int off = 32; off > 0; off >>= 1) s += __shfl_down(s, off);
    if ((t & 63) == 0) red[t >> 6] = s;
    __syncthreads();
    float bsum = red[0] + red[1] + red[2] + red[3];
    float w = e / bsum;
    scores[b * 256 + t] = w;
    attw_out[b * 256 + t] = w;
}

__global__ void __launch_bounds__(256)
att_context(const float* __restrict__ attw, const float* __restrict__ lout,
            float* __restrict__ ctx)
{
    int b = blockIdx.y;
    int j = blockIdx.x * 256 + threadIdx.x;
    float s = 0.f;
    for (int t = 0; t < 256; ++t)
        s += attw[b * 256 + t] * lout[((size_t)b * 256 + t) * 1024 + j];
    ctx[(size_t)b * 1024 + j] = s;
}

__global__ void __launch_bounds__(256)
fc1_kernel(const float* __restrict__ ctx, const float* __restrict__ cw1,
           const float* __restrict__ cb1, float* __restrict__ hid2)
{
    int idx = blockIdx.x * 256 + threadIdx.x;
    int b = idx >> 9, n = idx & 511;
    float s = cb1[n];
    const float* cr = ctx + (size_t)b * 1024;
    for (int k = 0; k < 1024; ++k)
        s = fmaf(cr[k], cw1[(size_t)k * 512 + n], s);
    hid2[idx] = fmaxf(s, 0.f);
}

__global__ void __launch_bounds__(256)
fc2_kernel(const float* __restrict__ hid2, const float* __restrict__ cw2,
           const float* __restrict__ cb2, float* __restrict__ logits)
{
    int idx = blockIdx.x * 256 + threadIdx.x;
    if (idx >= 12800) return;
    int b = idx / 100, n = idx % 100;
    float s = cb2[n];
    const float* hr = hid2 + (size_t)b * 512;
    for (int k = 0; k < 512; ++k)
        s = fmaf(hr[k], cw2[(size_t)k * 100 + n], s);
    logits[idx] = s;
}

extern "C" void kernel_launch(void* const* d_in, const int* in_sizes, int n_in,
                              void* d_out, int out_size, void* d_ws, size_t ws_size,
                              hipStream_t stream)
{
    const float* x        = (const float*)d_in[0];
    const float* w_ih_l0f = (const float*)d_in[1];
    const float* w_hh_l0f = (const float*)d_in[2];
    const float* b_l0f    = (const float*)d_in[3];
    const float* w_ih_l0b = (const float*)d_in[4];
    const float* w_hh_l0b = (const float*)d_in[5];
    const float* b_l0b    = (const float*)d_in[6];
    const float* w_ih_l1f = (const float*)d_in[7];
    const float* w_hh_l1f = (const float*)d_in[8];
    const float* b_l1f    = (const float*)d_in[9];
    const float* w_ih_l1b = (const float*)d_in[10];
    const float* w_hh_l1b = (const float*)d_in[11];
    const float* b_l1b    = (const float*)d_in[12];
    const float* aw1      = (const float*)d_in[13];
    const float* ab1      = (const float*)d_in[14];
    const float* aw2      = (const float*)d_in[15];
    const float* ab2      = (const float*)d_in[16];
    const float* cw1      = (const float*)d_in[17];
    const float* cb1      = (const float*)d_in[18];
    const float* cw2      = (const float*)d_in[19];
    const float* cb2      = (const float*)d_in[20];

    float* ws   = (float*)d_ws;
    float* bufA = ws;                      // 67,108,864 floats  (xproj fwd / att hidden)
    float* bufB = bufA + 67108864;         // 67,108,864         (xproj bwd / aw1^T)
    float* h0   = bufB + 67108864;         // 33,554,432  layer0 out [B,T,1024]
    float* lout = h0   + 33554432;         // 33,554,432  layer1 out
    float* cst  = lout + 33554432;         // 131,072     (reused: barrier counters)
    float* scores = cst + 131072;          // 32,768
    float* ctx  = scores + 32768;          // 131,072
    float* hid2 = ctx  + 131072;           // 65,536
    // h ping-pong split-bf16 planes: 4 x 131072 ushorts = 262144 floats
    float* hbase = hid2 + 65536;
    ushort* hA_hi = (ushort*)hbase;
    ushort* hA_lo = hA_hi + 131072;
    ushort* hB_hi = hA_lo + 131072;
    ushort* hB_lo = hB_hi + 131072;
    // packed w_hh split-bf16: per layer [2][64][32][512] hi + lo
    float* wbase = hbase + 262144;
    ushort* w0_hi = (ushort*)wbase;        // 2,097,152 ushorts
    ushort* w0_lo = w0_hi + 2097152;
    ushort* w1_hi = w0_lo + 2097152;
    ushort* w1_lo = w1_hi + 2097152;       // total wbase: 4,194,304 floats

    unsigned* bar = (unsigned*)cst;        // two grid-barrier counters

    float* logits   = (float*)d_out;
    float* attw_out = logits + 12800;

    dim3 blk(256);
    const size_t dstride = 64 * 32 * 512;  // per-dir stride in packed weights

    // persistent kernel needs >64 KB dynamic LDS
    static int lds_set = 0;
    if (!lds_set) {
        hipFuncSetAttribute((const void*)lstm_persist,
                            hipFuncAttributeMaxDynamicSharedMemorySize, PERSIST_LDS);
        lds_set = 1;
    }

    // ---- Pack recurrent weights (once per call) ----
    pack_whh32<<<2048, blk, 0, stream>>>(w_hh_l0f, w0_hi, w0_lo);
    pack_whh32<<<2048, blk, 0, stream>>>(w_hh_l0b, w0_hi + dstride, w0_lo + dstride);
    pack_whh32<<<2048, blk, 0, stream>>>(w_hh_l1f, w1_hi, w1_lo);
    pack_whh32<<<2048, blk, 0, stream>>>(w_hh_l1b, w1_hi + dstride, w1_lo + dstride);

    // ---- Layer 0 input projections ----
    gemm_mfma_bt<<<dim3(16, 256), blk, 0, stream>>>(x, 1662, w_ih_l0f, 1662, b_l0f, bufA, 2048L, 1662);
    gemm_mfma_bt<<<dim3(16, 256), blk, 0, stream>>>(x, 1662, w_ih_l0b, 1662, b_l0b, bufB, 2048L, 1662);

    // ---- Layer 0 recurrence: one persistent launch ----
    hipMemsetAsync(hA_hi, 0, 4 * 131072 * sizeof(ushort), stream);
    hipMemsetAsync(bar, 0, 2 * sizeof(unsigned), stream);
    lstm_persist<<<PERSIST_NBLK, blk, PERSIST_LDS, stream>>>(
        w0_hi, w0_lo, hA_hi, hA_lo, hB_hi, hB_lo, bufA, bufB, h0, bar);

    // ---- Layer 1 input projections ----
    gemm_mfma_bt<<<dim3(16, 256), blk, 0, stream>>>(h0, 1024, w_ih_l1f, 1024, b_l1f, bufA, 2048L, 1024);
    gemm_mfma_bt<<<dim3(16, 256), blk, 0, stream>>>(h0, 1024, w_ih_l1b, 1024, b_l1b, bufB, 2048L, 1024);

    // ---- Layer 1 recurrence ----
    hipMemsetAsync(hA_hi, 0, 4 * 131072 * sizeof(ushort), stream);
    lstm_persist<<<PERSIST_NBLK, blk, PERSIST_LDS, stream>>>(
        w1_hi, w1_lo, hA_hi, hA_lo, hB_hi, hB_lo, bufA, bufB, lout, bar + 1);

    // ---- Attention ----
    transpose1024<<<dim3(32, 32), blk, 0, stream>>>(aw1, bufB);
    gemm_mfma_bt<<<dim3(8, 256), blk, 0, stream>>>(lout, 1024, bufB, 1024, ab1, bufA, 1024L, 1024);

    att_score<<<32768, blk, 0, stream>>>(bufA, aw2, ab2, scores);
    att_softmax<<<128, blk, 0, stream>>>(scores, attw_out);
    att_context<<<dim3(4, 128), blk, 0, stream>>>(scores, lout, ctx);

    // ---- Classifier ----
    fc1_kernel<<<256, blk, 0, stream>>>(ctx, cw1, cb1, hid2);
    fc2_kernel<<<50, blk, 0, stream>>>(hid2, cw2, cb2, logits);
}

// Round 3
// 18568.854 us; speedup vs baseline: 1.4584x; 1.2969x over previous
//
#include <hip/hip_runtime.h>
#include <math.h>

// Problem constants: IN=1662, H=512, T=256, B=128, C=100
// Outputs: logits [128,100] then attw [128,256,1]

typedef __attribute__((ext_vector_type(8))) short bf16x8;
typedef __attribute__((ext_vector_type(4))) float f32x4;

__device__ __forceinline__ ushort f2bf(float f) {
    uint u = __float_as_uint(f);
    uint r = (u + 0x7FFFu + ((u >> 16) & 1u)) >> 16;
    return (ushort)r;
}
__device__ __forceinline__ float bf2f(ushort h) {
    return __uint_as_float(((uint)h) << 16);
}
__device__ __forceinline__ float sigm(float x) { return 1.f / (1.f + __expf(-x)); }
__device__ __forceinline__ float tanhfast(float x) {
    float xx = fminf(fmaxf(x, -9.f), 9.f);
    float e = __expf(2.f * xx);
    return (e - 1.f) / (e + 1.f);
}

// ---------------------------------------------------------------------------
// Split-bf16 MFMA GEMM: C[M,N] = A[M,K] @ W^T + bias   (unchanged)
// ---------------------------------------------------------------------------
__global__ void __launch_bounds__(256, 2)
gemm_mfma_bt(const float* __restrict__ A, int lda,
             const float* __restrict__ W, int ldw,
             const float* __restrict__ bias,
             float* __restrict__ C, long ldc, int K)
{
    __shared__ ushort Ahi[128][40];
    __shared__ ushort Alo[128][40];
    __shared__ ushort Bhi[128][40];
    __shared__ ushort Blo[128][40];

    const int tid  = threadIdx.x;
    const int bm   = blockIdx.y * 128;
    const int bn   = blockIdx.x * 128;
    const int wave = tid >> 6, lane = tid & 63;
    const int wr = wave >> 1, wc = wave & 1;
    const int quad = lane >> 4, l16 = lane & 15;

    f32x4 acc[4][4];
#pragma unroll
    for (int i = 0; i < 4; ++i)
#pragma unroll
        for (int j = 0; j < 4; ++j)
            acc[i][j] = (f32x4){0.f, 0.f, 0.f, 0.f};

    for (int k0 = 0; k0 < K; k0 += 32) {
        const int kw = (K - k0 < 32) ? (K - k0) : 32;
#pragma unroll
        for (int i = 0; i < 8; ++i) {
            int f = i * 256 + tid;
            int row = f >> 4, kp = f & 15;
            float2 v = make_float2(0.f, 0.f);
            if (2 * kp < kw)
                v = *(const float2*)(A + (size_t)(bm + row) * lda + k0 + 2 * kp);
            ushort hx = f2bf(v.x), hy = f2bf(v.y);
            ushort lx = f2bf(v.x - bf2f(hx)), ly = f2bf(v.y - bf2f(hy));
            *(uint*)&Ahi[row][2 * kp] = (uint)hx | ((uint)hy << 16);
            *(uint*)&Alo[row][2 * kp] = (uint)lx | ((uint)ly << 16);
        }
#pragma unroll
        for (int i = 0; i < 8; ++i) {
            int f = i * 256 + tid;
            int row = f >> 4, kp = f & 15;
            float2 v = make_float2(0.f, 0.f);
            if (2 * kp < kw)
                v = *(const float2*)(W + (size_t)(bn + row) * ldw + k0 + 2 * kp);
            ushort hx = f2bf(v.x), hy = f2bf(v.y);
            ushort lx = f2bf(v.x - bf2f(hx)), ly = f2bf(v.y - bf2f(hy));
            *(uint*)&Bhi[row][2 * kp] = (uint)hx | ((uint)hy << 16);
            *(uint*)&Blo[row][2 * kp] = (uint)lx | ((uint)ly << 16);
        }
        __syncthreads();

        bf16x8 ah[4], al[4], bh[4], bl[4];
#pragma unroll
        for (int i = 0; i < 4; ++i) {
            int m = wr * 64 + i * 16 + l16;
            ah[i] = *(const bf16x8*)&Ahi[m][quad * 8];
            al[i] = *(const bf16x8*)&Alo[m][quad * 8];
            int n = wc * 64 + i * 16 + l16;
            bh[i] = *(const bf16x8*)&Bhi[n][quad * 8];
            bl[i] = *(const bf16x8*)&Blo[n][quad * 8];
        }
#pragma unroll
        for (int i = 0; i < 4; ++i)
#pragma unroll
            for (int j = 0; j < 4; ++j) {
                acc[i][j] = __builtin_amdgcn_mfma_f32_16x16x32_bf16(ah[i], bh[j], acc[i][j], 0, 0, 0);
                acc[i][j] = __builtin_amdgcn_mfma_f32_16x16x32_bf16(ah[i], bl[j], acc[i][j], 0, 0, 0);
                acc[i][j] = __builtin_amdgcn_mfma_f32_16x16x32_bf16(al[i], bh[j], acc[i][j], 0, 0, 0);
            }
        __syncthreads();
    }

#pragma unroll
    for (int j = 0; j < 4; ++j) {
        int n = bn + wc * 64 + j * 16 + l16;
        float bv = bias ? bias[n] : 0.f;
#pragma unroll
        for (int i = 0; i < 4; ++i) {
            int mb = bm + wr * 64 + i * 16 + quad * 4;
#pragma unroll
            for (int r = 0; r < 4; ++r)
                C[(size_t)(mb + r) * ldc + n] = acc[i][j][r] + bv;
        }
    }
}

// 1024x1024 transpose: out[n][k] = in[k][n]
__global__ void __launch_bounds__(256)
transpose1024(const float* __restrict__ in, float* __restrict__ out)
{
    __shared__ float tile[32][33];
    int bx = blockIdx.x * 32, by = blockIdx.y * 32;
    int tx = threadIdx.x & 31, ty = threadIdx.x >> 5;
    for (int i = 0; i < 32; i += 8)
        tile[ty + i][tx] = in[(size_t)(by + ty + i) * 1024 + bx + tx];
    __syncthreads();
    for (int i = 0; i < 32; i += 8)
        out[(size_t)(bx + ty + i) * 1024 + by + tx] = tile[tx][ty + i];
}

// ---------------------------------------------------------------------------
// Pack w_hh [2048,512] fp32 (one direction) -> gate-packed split-bf16 planes
//   dest [64 jg][32 p][512 k], p = g*8 + (j&7), jg = j>>3, row = g*512 + j
// ---------------------------------------------------------------------------
__global__ void __launch_bounds__(256)
pack_whh32(const float* __restrict__ w, ushort* __restrict__ hi, ushort* __restrict__ lo)
{
    int idx = blockIdx.x * 256 + threadIdx.x;     // 2048*256 = 524288
    int r = idx >> 8;
    int kp = (idx & 255) * 2;
    float2 v = *(const float2*)&w[(size_t)r * 512 + kp];
    int g = r >> 9, j = r & 511, jg = j >> 3, jj = j & 7;
    int p = g * 8 + jj;
    size_t o = ((size_t)jg * 32 + p) * 512 + kp;
    ushort hx = f2bf(v.x), hy = f2bf(v.y);
    *(uint*)&hi[o] = (uint)hx | ((uint)hy << 16);
    *(uint*)&lo[o] = (uint)f2bf(v.x - bf2f(hx)) | ((uint)f2bf(v.y - bf2f(hy)) << 16);
}

// ---------------------------------------------------------------------------
// Persistent LSTM layer, fence-free coherent version.
// h-state moves through Infinity Cache via sc0/sc1 (L1+L2-bypass) loads and
// write-through stores -> NO L2 writeback/invalidate at the grid barrier.
// Signal: relaxed agent-scope RMW (reaches coherent point; proven R1).
// Spin: explicit asm sc0/sc1 load each poll (never caches a stale line).
// ---------------------------------------------------------------------------
#define PERSIST_NBLK 128
#define PERSIST_LDS  (65536 + 128 * 36 * 4)   // weights 64KB + zbuf [128][36]

__device__ __forceinline__ void issue_group(bf16x8 (&f)[16],
                                            const ushort* hh, const ushort* hl,
                                            int m0, int quad, int c0)
{
#pragma unroll
    for (int u = 0; u < 4; ++u) {
        const int k = (c0 + u) * 32 + quad * 8;
        const ushort* p0 = &hh[(size_t)m0 * 512 + k];
        const ushort* p1 = &hh[(size_t)(m0 + 16) * 512 + k];
        const ushort* p2 = &hl[(size_t)m0 * 512 + k];
        const ushort* p3 = &hl[(size_t)(m0 + 16) * 512 + k];
        asm volatile("global_load_dwordx4 %0, %1, off sc0 sc1" : "=v"(f[4 * u + 0]) : "v"(p0) : "memory");
        asm volatile("global_load_dwordx4 %0, %1, off sc0 sc1" : "=v"(f[4 * u + 1]) : "v"(p1) : "memory");
        asm volatile("global_load_dwordx4 %0, %1, off sc0 sc1" : "=v"(f[4 * u + 2]) : "v"(p2) : "memory");
        asm volatile("global_load_dwordx4 %0, %1, off sc0 sc1" : "=v"(f[4 * u + 3]) : "v"(p3) : "memory");
    }
}

__device__ __forceinline__ void mfma_group(const bf16x8 (&f)[16],
                                           const ushort* wlds, int l16, int quad,
                                           int c0, f32x4 (&acc)[2][2])
{
#pragma unroll
    for (int u = 0; u < 4; ++u) {
        const int k = (c0 + u) * 32 + quad * 8;
#pragma unroll
        for (int nt = 0; nt < 2; ++nt) {
            int p  = nt * 16 + l16;
            int wi = ((p << 9) + k) ^ ((p & 7) << 3);
            bf16x8 bh = *(const bf16x8*)&wlds[wi];
            bf16x8 bl = *(const bf16x8*)&wlds[16384 + wi];
            acc[0][nt] = __builtin_amdgcn_mfma_f32_16x16x32_bf16(f[4 * u + 0], bh, acc[0][nt], 0, 0, 0);
            acc[0][nt] = __builtin_amdgcn_mfma_f32_16x16x32_bf16(f[4 * u + 0], bl, acc[0][nt], 0, 0, 0);
            acc[0][nt] = __builtin_amdgcn_mfma_f32_16x16x32_bf16(f[4 * u + 2], bh, acc[0][nt], 0, 0, 0);
            acc[1][nt] = __builtin_amdgcn_mfma_f32_16x16x32_bf16(f[4 * u + 1], bh, acc[1][nt], 0, 0, 0);
            acc[1][nt] = __builtin_amdgcn_mfma_f32_16x16x32_bf16(f[4 * u + 1], bl, acc[1][nt], 0, 0, 0);
            acc[1][nt] = __builtin_amdgcn_mfma_f32_16x16x32_bf16(f[4 * u + 3], bh, acc[1][nt], 0, 0, 0);
        }
    }
}

#define WAITV(n) do { asm volatile("s_waitcnt vmcnt(" #n ")" ::: "memory"); \
                      __builtin_amdgcn_sched_barrier(0); } while (0)

__global__ void __launch_bounds__(256)
lstm_persist(const ushort* __restrict__ w_hi, const ushort* __restrict__ w_lo, // [2][64][32][512]
             ushort* __restrict__ hA_hi, ushort* __restrict__ hA_lo,
             ushort* __restrict__ hB_hi, ushort* __restrict__ hB_lo,
             const float* __restrict__ xf, const float* __restrict__ xb,  // xproj per dir [B*T,2048]
             float* __restrict__ out,    // [B,T,1024]
             unsigned* __restrict__ bar) // [2] per-direction counters
{
    extern __shared__ __align__(16) char smem[];
    ushort* wlds = (ushort*)smem;            // [hi 16384][lo 16384] ushorts, swizzled
    float*  zbuf = (float*)(smem + 65536);   // [128][36]

    const int tid  = threadIdx.x;
    const int dir  = blockIdx.x >> 6;
    const int jg   = blockIdx.x & 63;
    const int wave = tid >> 6, lane = tid & 63;
    const int quad = lane >> 4, l16 = lane & 15;
    unsigned* barp = bar + dir;

    // ---- one-time: stage this block's weight slice into LDS (swizzled) ----
    {
        const ushort* wh = w_hi + ((size_t)dir * 64 + jg) * (32 * 512);
        const ushort* wl = w_lo + ((size_t)dir * 64 + jg) * (32 * 512);
#pragma unroll
        for (int it = 0; it < 8; ++it) {
            int unit = it * 256 + tid;           // 2048 x 16B units per plane
            int p = unit >> 6, k8 = unit & 63;
            int src = p * 512 + k8 * 8;          // ushort index
            int dst = src ^ ((p & 7) << 3);      // XOR-swizzle (16B granules)
            *(uint4*)&wlds[dst]         = *(const uint4*)&wh[src];
            *(uint4*)&wlds[16384 + dst] = *(const uint4*)&wl[src];
        }
    }

    // gate-phase mapping: thread -> batch b, 4 j's starting at jb
    const int b  = tid >> 1;
    const int jb = (tid & 1) * 4;
    const int j0 = jg * 8 + jb;                  // global j (within H=512)
    const float* xbase = dir ? xb : xf;
    float cv[4] = {0.f, 0.f, 0.f, 0.f};          // c-state lives in registers

    const int m0 = wave * 32 + l16;              // A-fragment rows for this wave
    const size_t doff = (size_t)dir * 65536;
    __syncthreads();

    for (int t = 0; t < 256; ++t) {
        const int teff = dir ? (255 - t) : t;

        // xproj loads (plain cached; independent of h)
        const float* xp = xbase + ((size_t)b * 256 + teff) * 2048 + j0;
        f32x4 xi, xF, xg, xo;
        asm volatile("global_load_dwordx4 %0, %1, off" : "=v"(xi) : "v"(xp) : "memory");
        asm volatile("global_load_dwordx4 %0, %1, off" : "=v"(xF) : "v"(xp + 512) : "memory");
        asm volatile("global_load_dwordx4 %0, %1, off" : "=v"(xg) : "v"(xp + 1024) : "memory");
        asm volatile("global_load_dwordx4 %0, %1, off" : "=v"(xo) : "v"(xp + 1536) : "memory");

        const ushort* hh = ((t & 1) ? hB_hi : hA_hi) + doff;
        const ushort* hl = ((t & 1) ? hB_lo : hA_lo) + doff;

        f32x4 acc[2][2];
#pragma unroll
        for (int mt = 0; mt < 2; ++mt)
#pragma unroll
            for (int nt = 0; nt < 2; ++nt)
                acc[mt][nt] = (f32x4){0.f, 0.f, 0.f, 0.f};

        // ---- pipelined A-fragment loads (IC-coherent) + MFMA ----
        bf16x8 fA[16], fB[16];
        issue_group(fA, hh, hl, m0, quad, 0);
        issue_group(fB, hh, hl, m0, quad, 4);
        WAITV(16);                                 // xproj + fA(c0) complete
        mfma_group(fA, wlds, l16, quad, 0, acc);
        issue_group(fA, hh, hl, m0, quad, 8);
        WAITV(16);                                 // fB(c4) complete
        mfma_group(fB, wlds, l16, quad, 4, acc);
        issue_group(fB, hh, hl, m0, quad, 12);
        WAITV(16);                                 // fA(c8) complete
        mfma_group(fA, wlds, l16, quad, 8, acc);
        WAITV(0);                                  // fB(c12) complete
        mfma_group(fB, wlds, l16, quad, 12, acc);

        // C/D layout: col = lane&15 (= packed p within n-tile), row = quad*4+r
#pragma unroll
        for (int mt = 0; mt < 2; ++mt)
#pragma unroll
            for (int nt = 0; nt < 2; ++nt)
#pragma unroll
                for (int r = 0; r < 4; ++r)
                    zbuf[(wave * 32 + mt * 16 + quad * 4 + r) * 36 + nt * 16 + l16] = acc[mt][nt][r];
        __syncthreads();

        // ---- gate phase (z = zbuf + xproj; c,h update) ----
        f32x4 hvv;
        ushort hhi[4];
        ushort hlo[4];
#pragma unroll
        for (int q = 0; q < 4; ++q) {
            int jj = jb + q;
            float vi = zbuf[b * 36 +      jj] + xi[q];
            float vf = zbuf[b * 36 +  8 + jj] + xF[q];
            float vg = zbuf[b * 36 + 16 + jj] + xg[q];
            float vo = zbuf[b * 36 + 24 + jj] + xo[q];
            float c  = sigm(vf) * cv[q] + sigm(vi) * tanhfast(vg);
            cv[q] = c;
            float h = sigm(vo) * tanhfast(c);
            hvv[q] = h;
            ushort hi = f2bf(h);
            hhi[q] = hi;
            hlo[q] = f2bf(h - bf2f(hi));
        }
        {
            size_t hoff = doff + (size_t)b * 512 + j0;
            ushort* oh = ((t & 1) ? hA_hi : hB_hi) + hoff;
            ushort* ol = ((t & 1) ? hA_lo : hB_lo) + hoff;
            uint2 vhi = make_uint2((uint)hhi[0] | ((uint)hhi[1] << 16),
                                   (uint)hhi[2] | ((uint)hhi[3] << 16));
            uint2 vlo = make_uint2((uint)hlo[0] | ((uint)hlo[1] << 16),
                                   (uint)hlo[2] | ((uint)hlo[3] << 16));
            asm volatile("global_store_dwordx2 %0, %1, off sc0 sc1" :: "v"(oh), "v"(vhi) : "memory");
            asm volatile("global_store_dwordx2 %0, %1, off sc0 sc1" :: "v"(ol), "v"(vlo) : "memory");
            float* op = out + ((size_t)b * 256 + teff) * 1024 + (size_t)dir * 512 + j0;
            *(f32x4*)op = hvv;
        }

        // ---- fence-free grid barrier (per direction, 64 blocks) ----
        asm volatile("s_waitcnt vmcnt(0) lgkmcnt(0)" ::: "memory");
        __syncthreads();
        if (tid == 0) {
            __hip_atomic_fetch_add(barp, 1u, __ATOMIC_RELAXED, __HIP_MEMORY_SCOPE_AGENT);
            unsigned tgt = 64u * (unsigned)(t + 1);
            unsigned cur;
            do {
                __builtin_amdgcn_s_sleep(2);
                // coherent poll: bypasses L1/L2 every iteration (cannot go stale)
                asm volatile("global_load_dword %0, %1, off sc0 sc1\n\t"
                             "s_waitcnt vmcnt(0)"
                             : "=v"(cur) : "v"(barp) : "memory");
            } while (cur < tgt);
        }
        __syncthreads();
    }
}

// ------------------------- attention / classifier tail ---------------------
__global__ void __launch_bounds__(256)
att_score(const float* __restrict__ hidden, const float* __restrict__ aw2,
          const float* __restrict__ ab2, float* __restrict__ scores)
{
    int row = blockIdx.x;
    const float* hrow = hidden + (size_t)row * 1024;
    int tid = threadIdx.x;
    float s = 0.f;
    for (int j = tid; j < 1024; j += 256)
        s += tanhf(hrow[j]) * aw2[j];
    for (int off = 32; off > 0; off >>= 1) s += __shfl_down(s, off);
    __shared__ float red[4];
    if ((tid & 63) == 0) red[tid >> 6] = s;
    __syncthreads();
    if (tid == 0)
        scores[row] = red[0] + red[1] + red[2] + red[3] + ab2[0];
}

__global__ void __launch_bounds__(256)
att_softmax(float* __restrict__ scores, float* __restrict__ attw_out)
{
    int b = blockIdx.x, t = threadIdx.x;
    float v = scores[b * 256 + t];
    __shared__ float red[4];
    float m = v;
    for (int off = 32; off > 0; off >>= 1) m = fmaxf(m, __shfl_down(m, off));
    if ((t & 63) == 0) red[t >> 6] = m;
    __syncthreads();
    float bmax = fmaxf(fmaxf(red[0], red[1]), fmaxf(red[2], red[3]));
    __syncthreads();
    float e = expf(v - bmax);
    float s = e;
    for (int off = 32; off > 0; off >>= 1) s += __shfl_down(s, off);
    if ((t & 63) == 0) red[t >> 6] = s;
    __syncthreads();
    float bsum = red[0] + red[1] + red[2] + red[3];
    float w = e / bsum;
    scores[b * 256 + t] = w;
    attw_out[b * 256 + t] = w;
}

__global__ void __launch_bounds__(256)
att_context(const float* __restrict__ attw, const float* __restrict__ lout,
            float* __restrict__ ctx)
{
    int b = blockIdx.y;
    int j = blockIdx.x * 256 + threadIdx.x;
    float s = 0.f;
    for (int t = 0; t < 256; ++t)
        s += attw[b * 256 + t] * lout[((size_t)b * 256 + t) * 1024 + j];
    ctx[(size_t)b * 1024 + j] = s;
}

__global__ void __launch_bounds__(256)
fc1_kernel(const float* __restrict__ ctx, const float* __restrict__ cw1,
           const float* __restrict__ cb1, float* __restrict__ hid2)
{
    int idx = blockIdx.x * 256 + threadIdx.x;
    int b = idx >> 9, n = idx & 511;
    float s = cb1[n];
    const float* cr = ctx + (size_t)b * 1024;
    for (int k = 0; k < 1024; ++k)
        s = fmaf(cr[k], cw1[(size_t)k * 512 + n], s);
    hid2[idx] = fmaxf(s, 0.f);
}

__global__ void __launch_bounds__(256)
fc2_kernel(const float* __restrict__ hid2, const float* __restrict__ cw2,
           const float* __restrict__ cb2, float* __restrict__ logits)
{
    int idx = blockIdx.x * 256 + threadIdx.x;
    if (idx >= 12800) return;
    int b = idx / 100, n = idx % 100;
    float s = cb2[n];
    const float* hr = hid2 + (size_t)b * 512;
    for (int k = 0; k < 512; ++k)
        s = fmaf(hr[k], cw2[(size_t)k * 100 + n], s);
    logits[idx] = s;
}

extern "C" void kernel_launch(void* const* d_in, const int* in_sizes, int n_in,
                              void* d_out, int out_size, void* d_ws, size_t ws_size,
                              hipStream_t stream)
{
    const float* x        = (const float*)d_in[0];
    const float* w_ih_l0f = (const float*)d_in[1];
    const float* w_hh_l0f = (const float*)d_in[2];
    const float* b_l0f    = (const float*)d_in[3];
    const float* w_ih_l0b = (const float*)d_in[4];
    const float* w_hh_l0b = (const float*)d_in[5];
    const float* b_l0b    = (const float*)d_in[6];
    const float* w_ih_l1f = (const float*)d_in[7];
    const float* w_hh_l1f = (const float*)d_in[8];
    const float* b_l1f    = (const float*)d_in[9];
    const float* w_ih_l1b = (const float*)d_in[10];
    const float* w_hh_l1b = (const float*)d_in[11];
    const float* b_l1b    = (const float*)d_in[12];
    const float* aw1      = (const float*)d_in[13];
    const float* ab1      = (const float*)d_in[14];
    const float* aw2      = (const float*)d_in[15];
    const float* ab2      = (const float*)d_in[16];
    const float* cw1      = (const float*)d_in[17];
    const float* cb1      = (const float*)d_in[18];
    const float* cw2      = (const float*)d_in[19];
    const float* cb2      = (const float*)d_in[20];

    float* ws   = (float*)d_ws;
    float* bufA = ws;                      // 67,108,864 floats  (xproj fwd / att hidden)
    float* bufB = bufA + 67108864;         // 67,108,864         (xproj bwd / aw1^T)
    float* h0   = bufB + 67108864;         // 33,554,432  layer0 out [B,T,1024]
    float* lout = h0   + 33554432;         // 33,554,432  layer1 out
    float* cst  = lout + 33554432;         // 131,072     (reused: barrier counters)
    float* scores = cst + 131072;          // 32,768
    float* ctx  = scores + 32768;          // 131,072
    float* hid2 = ctx  + 131072;           // 65,536
    // h ping-pong split-bf16 planes: 4 x 131072 ushorts = 262144 floats
    float* hbase = hid2 + 65536;
    ushort* hA_hi = (ushort*)hbase;
    ushort* hA_lo = hA_hi + 131072;
    ushort* hB_hi = hA_lo + 131072;
    ushort* hB_lo = hB_hi + 131072;
    // packed w_hh split-bf16: per layer [2][64][32][512] hi + lo
    float* wbase = hbase + 262144;
    ushort* w0_hi = (ushort*)wbase;        // 2,097,152 ushorts
    ushort* w0_lo = w0_hi + 2097152;
    ushort* w1_hi = w0_lo + 2097152;
    ushort* w1_lo = w1_hi + 2097152;       // total wbase: 4,194,304 floats

    unsigned* bar = (unsigned*)cst;        // 4 grid-barrier counters (layer x dir)

    float* logits   = (float*)d_out;
    float* attw_out = logits + 12800;

    dim3 blk(256);
    const size_t dstride = 64 * 32 * 512;  // per-dir stride in packed weights

    // persistent kernel needs >64 KB dynamic LDS
    static int lds_set = 0;
    if (!lds_set) {
        hipFuncSetAttribute((const void*)lstm_persist,
                            hipFuncAttributeMaxDynamicSharedMemorySize, PERSIST_LDS);
        lds_set = 1;
    }

    // ---- Pack recurrent weights (once per call) ----
    pack_whh32<<<2048, blk, 0, stream>>>(w_hh_l0f, w0_hi, w0_lo);
    pack_whh32<<<2048, blk, 0, stream>>>(w_hh_l0b, w0_hi + dstride, w0_lo + dstride);
    pack_whh32<<<2048, blk, 0, stream>>>(w_hh_l1f, w1_hi, w1_lo);
    pack_whh32<<<2048, blk, 0, stream>>>(w_hh_l1b, w1_hi + dstride, w1_lo + dstride);

    // ---- Layer 0 input projections ----
    gemm_mfma_bt<<<dim3(16, 256), blk, 0, stream>>>(x, 1662, w_ih_l0f, 1662, b_l0f, bufA, 2048L, 1662);
    gemm_mfma_bt<<<dim3(16, 256), blk, 0, stream>>>(x, 1662, w_ih_l0b, 1662, b_l0b, bufB, 2048L, 1662);

    // ---- Layer 0 recurrence: one persistent launch ----
    hipMemsetAsync(hA_hi, 0, 4 * 131072 * sizeof(ushort), stream);
    hipMemsetAsync(bar, 0, 4 * sizeof(unsigned), stream);
    lstm_persist<<<PERSIST_NBLK, blk, PERSIST_LDS, stream>>>(
        w0_hi, w0_lo, hA_hi, hA_lo, hB_hi, hB_lo, bufA, bufB, h0, bar);

    // ---- Layer 1 input projections ----
    gemm_mfma_bt<<<dim3(16, 256), blk, 0, stream>>>(h0, 1024, w_ih_l1f, 1024, b_l1f, bufA, 2048L, 1024);
    gemm_mfma_bt<<<dim3(16, 256), blk, 0, stream>>>(h0, 1024, w_ih_l1b, 1024, b_l1b, bufB, 2048L, 1024);

    // ---- Layer 1 recurrence ----
    hipMemsetAsync(hA_hi, 0, 4 * 131072 * sizeof(ushort), stream);
    lstm_persist<<<PERSIST_NBLK, blk, PERSIST_LDS, stream>>>(
        w1_hi, w1_lo, hA_hi, hA_lo, hB_hi, hB_lo, bufA, bufB, lout, bar + 2);

    // ---- Attention ----
    transpose1024<<<dim3(32, 32), blk, 0, stream>>>(aw1, bufB);
    gemm_mfma_bt<<<dim3(8, 256), blk, 0, stream>>>(lout, 1024, bufB, 1024, ab1, bufA, 1024L, 1024);

    att_score<<<32768, blk, 0, stream>>>(bufA, aw2, ab2, scores);
    att_softmax<<<128, blk, 0, stream>>>(scores, attw_out);
    att_context<<<dim3(4, 128), blk, 0, stream>>>(scores, lout, ctx);

    // ---- Classifier ----
    fc1_kernel<<<256, blk, 0, stream>>>(ctx, cw1, cb1, hid2);
    fc2_kernel<<<50, blk, 0, stream>>>(hid2, cw2, cb2, logits);
}